// Round 2
// 712.932 us; speedup vs baseline: 1.0482x; 1.0482x over previous
//
#include <hip/hip_runtime.h>

// GsumLayer: out[b] = a[b] @ x[b], B=8, N=4096, D=32, fp32 in/out.
//
// Role-swapped split-bf16 MFMA design:
//   D[d][n] = sum_k x[k][d] * a[n][k]
//   A-operand (M=16) = x side  (lane: row d = l&15, k = (l>>4)*8+e)  <- from LDS
//   B-operand (N=16) = a side  (lane: col n = l&15, k = (l>>4)*8+e)  <- 8 contiguous
//     fp32 from one a-row: the 537 MB a-stream goes HBM -> VGPR directly,
//     2-deep software pipeline, no LDS round trip, no barriers on the stream.
//   Split a,x ~= hi+lo (bf16); keep hi*hi + lo*hi + hi*lo (3 MFMAs/term-set).
//   x[b] (512 KB, L2-resident) is staged per 256-wide K-chunk into LDS,
//   transposed to [d][k] bf16 hi/lo with +8-short row pad (conflict-free b128
//   fragment reads), double-buffered, one s_barrier+lgkmcnt per chunk (raw,
//   no vmcnt drain -> a-prefetch stays in flight across chunks).
//
// De-risked vs previous round: single kernel, no d_ws, no global_load_lds,
// all addresses in-bounds (a-prefetch wraps k mod 4096).
//
// Input order per setup_inputs(): d_in[0] = x [B,N,D], d_in[1] = a [B,N,N].

#define GN 4096
#define GD 32
#define GB 8
#define BK 256            // K per chunk
#define NCH (GN / BK)     // 16 chunks
#define NT 512            // threads (8 waves)
#define TILE_N 128        // n-rows per block (8 waves x 16)
#define PK (BK + 8)       // padded k-shorts per d-row (264): breaks pow2 stride

typedef float f32x4 __attribute__((ext_vector_type(4)));
typedef short s16x8 __attribute__((ext_vector_type(8)));

__global__ __launch_bounds__(NT, 2) void gsum_mfma(
    const float* __restrict__ x,   // [B][N][D]
    const float* __restrict__ a,   // [B][N][N]
    float* __restrict__ out)       // [B][N][D]
{
    __shared__ __align__(16) unsigned short Xh[2][GD][PK];  // 2 x 16.5 KB
    __shared__ __align__(16) unsigned short Xl[2][GD][PK];  // 2 x 16.5 KB

    const int t  = threadIdx.x;
    const int w  = t >> 6;        // wave 0..7
    const int l  = t & 63;
    const int m  = l & 15;        // MFMA row/col index
    const int kg = l >> 4;        // MFMA k-group 0..3

    const int b    = blockIdx.x >> 5;       // batch
    const int tile = blockIdx.x & 31;       // 32 row-tiles of 128
    const int n0   = tile * TILE_N + w * 16;

    const float* Xb = x + (long long)b * GN * GD;
    // per-lane a-row base: row n0+m, k-offset kg*8
    const float* arow = a + ((long long)b * GN + n0 + m) * GN + kg * 8;

    // x staging mapping: thread t stages x[k0+kr][c0..c0+15]
    const int kr = t >> 1;          // 0..255
    const int c0 = (t & 1) * 16;    // d-half

    f32x4 acc0 = {0.f, 0.f, 0.f, 0.f};
    f32x4 acc1 = {0.f, 0.f, 0.f, 0.f};

    // ---- x chunk staging helpers ------------------------------------
    auto XLOAD = [&](int k0, float4* xr) {
        const float* p = Xb + (long long)(k0 + kr) * GD + c0;
        xr[0] = *(const float4*)(p);
        xr[1] = *(const float4*)(p + 4);
        xr[2] = *(const float4*)(p + 8);
        xr[3] = *(const float4*)(p + 12);
    };
    auto XWRITE = [&](int nb, const float4* xr) {
        #pragma unroll
        for (int q = 0; q < 4; ++q) {
            const float fv[4] = {xr[q].x, xr[q].y, xr[q].z, xr[q].w};
            #pragma unroll
            for (int j = 0; j < 4; ++j) {
                const int d = c0 + q * 4 + j;
                unsigned u  = __float_as_uint(fv[j]);
                unsigned hb = (u + 0x8000u) >> 16;              // round-half-up bf16
                float hif   = __uint_as_float(hb << 16);
                unsigned lb = (__float_as_uint(fv[j] - hif) + 0x8000u) >> 16;
                Xh[nb][d][kr] = (unsigned short)hb;
                Xl[nb][d][kr] = (unsigned short)lb;
            }
        }
    };
    // a prefetch: 8 contiguous fp32 of this lane's row at global k (wrapped)
    auto ALOAD = [&](f32x4* dst, int k) {
        const int kc = (k >= GN) ? (k - GN) : k;   // wrap: always in-bounds
        const float* p = arow + kc;
        dst[0] = *(const f32x4*)(p);
        dst[1] = *(const f32x4*)(p + 4);
    };

    // ---- prologue: stage chunk 0, preload a-pipeline ----------------
    {
        float4 xr[4];
        XLOAD(0, xr);
        XWRITE(0, xr);
    }
    f32x4 pa[2][2];
    ALOAD(pa[0], 0);
    ALOAD(pa[1], 32);
    asm volatile("s_waitcnt lgkmcnt(0)" ::: "memory");
    __builtin_amdgcn_s_barrier();

    // ---- main chunk loop --------------------------------------------
    for (int c = 0; c < NCH; ++c) {
        const int nb = c & 1;
        const int k0 = c * BK;

        float4 xnext[4];
        if (c + 1 < NCH) XLOAD(k0 + BK, xnext);   // issue early; consumed post-compute

        #pragma unroll
        for (int s = 0; s < 8; ++s) {
            // consume pipeline stage, then refill it for step s+2
            float av[8];
            #pragma unroll
            for (int e = 0; e < 4; ++e) {
                av[e]     = pa[s & 1][0][e];
                av[4 + e] = pa[s & 1][1][e];
            }
            ALOAD(pa[s & 1], k0 + s * 32 + 64);

            // convert a 8 elems -> bf16 hi/lo
            s16x8 ahi, alo;
            #pragma unroll
            for (int e = 0; e < 8; ++e) {
                unsigned u  = __float_as_uint(av[e]);
                unsigned hb = (u + 0x8000u) >> 16;
                ahi[e] = (short)hb;
                float hif = __uint_as_float(hb << 16);
                alo[e] = (short)((__float_as_uint(av[e] - hif) + 0x8000u) >> 16);
            }

            // x fragments (conflict-free b128: pad PK=264)
            const int kk = s * 32 + kg * 8;
            s16x8 xh0 = *(const s16x8*)&Xh[nb][m][kk];
            s16x8 xl0 = *(const s16x8*)&Xl[nb][m][kk];
            s16x8 xh1 = *(const s16x8*)&Xh[nb][16 + m][kk];
            s16x8 xl1 = *(const s16x8*)&Xl[nb][16 + m][kk];

            // 3-term split, two d-halves
            acc0 = __builtin_amdgcn_mfma_f32_16x16x32_bf16(xh0, ahi, acc0, 0, 0, 0);
            acc1 = __builtin_amdgcn_mfma_f32_16x16x32_bf16(xh1, ahi, acc1, 0, 0, 0);
            acc0 = __builtin_amdgcn_mfma_f32_16x16x32_bf16(xl0, ahi, acc0, 0, 0, 0);
            acc1 = __builtin_amdgcn_mfma_f32_16x16x32_bf16(xl1, ahi, acc1, 0, 0, 0);
            acc0 = __builtin_amdgcn_mfma_f32_16x16x32_bf16(xh0, alo, acc0, 0, 0, 0);
            acc1 = __builtin_amdgcn_mfma_f32_16x16x32_bf16(xh1, alo, acc1, 0, 0, 0);
        }

        if (c + 1 < NCH) XWRITE((c + 1) & 1, xnext);
        asm volatile("s_waitcnt lgkmcnt(0)" ::: "memory");
        __builtin_amdgcn_s_barrier();
    }

    // ---- epilogue: C/D layout col=lane&15, row=(lane>>4)*4+reg ------
    // D row (M) = d within half; D col (N) = n within wave tile.
    float* Ob = out + ((long long)b * GN + n0 + m) * GD + kg * 4;
    #pragma unroll
    for (int j = 0; j < 4; ++j) {
        Ob[j]      = acc0[j];   // d = kg*4 + j
        Ob[16 + j] = acc1[j];   // d = 16 + kg*4 + j
    }
}

extern "C" void kernel_launch(void* const* d_in, const int* in_sizes, int n_in,
                              void* d_out, int out_size, void* d_ws, size_t ws_size,
                              hipStream_t stream) {
    const float* x = (const float*)d_in[0];  // [B, N, D]
    const float* a = (const float*)d_in[1];  // [B, N, N]
    float* out = (float*)d_out;              // [B, N, D]

    dim3 grid(GB * (GN / TILE_N));  // 8 * 32 = 256 blocks, 2 blocks/CU capacity
    dim3 block(NT);                 // 512 threads = 8 waves
    gsum_mfma<<<grid, block, 0, stream>>>(x, a, out);
}